// Round 12
// baseline (263.140 us; speedup 1.0000x reference)
//
#include <hip/hip_runtime.h>

#define NCH 128
#define NGRAPH 64
#define SUB 16
#define CAP 64          // per-node edge bucket capacity (max in-degree ~45 for Poisson(16))

typedef _Float16 h8 __attribute__((ext_vector_type(8)));
typedef float f32x4 __attribute__((ext_vector_type(4)));
typedef float f32x2 __attribute__((ext_vector_type(2)));

// ---------------- f16/fp4 helpers ----------------

__device__ __forceinline__ unsigned pkh(float a, float b) {
    union { _Float16 h[2]; unsigned u; } x;
    x.h[0] = (_Float16)a; x.h[1] = (_Float16)b;
    return x.u;
}
__device__ __forceinline__ float flo(unsigned u) {
    union { unsigned u; _Float16 h[2]; } x; x.u = u; return (float)x.h[0];
}
__device__ __forceinline__ float fhi(unsigned u) {
    union { unsigned u; _Float16 h[2]; } x; x.u = u; return (float)x.h[1];
}
__device__ __forceinline__ unsigned short h16(float a) {
    union { _Float16 h; unsigned short s; } x; x.h = (_Float16)a; return x.s;
}

// fp4 e2m1 pair encode/decode with power-of-2 scale (MX-style).
// Prefer gfx950 HW cvt_scalef32 ops; manual fallback if builtins missing.
__device__ __forceinline__ unsigned fp4_enc_byte(float v0, float v1, float s) {
#if __has_builtin(__builtin_amdgcn_cvt_scalef32_pk_fp4_f32)
    return __builtin_amdgcn_cvt_scalef32_pk_fp4_f32(0u, v0, v1, s, 0) & 0xffu;
#else
    float rs = 1.0f / s;
    float t0 = v0 * rs, t1 = v1 * rs;
    float a0 = fabsf(t0), a1 = fabsf(t1);
    unsigned n0 = (a0 >= 0.25f) + (a0 >= 0.75f) + (a0 >= 1.25f) + (a0 >= 1.75f)
                + (a0 >= 2.5f) + (a0 >= 3.5f) + (a0 >= 5.0f);
    unsigned n1 = (a1 >= 0.25f) + (a1 >= 0.75f) + (a1 >= 1.25f) + (a1 >= 1.75f)
                + (a1 >= 2.5f) + (a1 >= 3.5f) + (a1 >= 5.0f);
    n0 |= (t0 < 0.f) ? 8u : 0u;
    n1 |= (t1 < 0.f) ? 8u : 0u;
    return n0 | (n1 << 4);
#endif
}
__device__ __forceinline__ float fp4_dec1(unsigned n) {
    unsigned m = n & 7u;
    float v = (m < 2u) ? 0.5f * (float)m
                       : ldexpf(1.0f + 0.5f * (float)(m & 1u), (int)(m >> 1) - 1);
    return (n & 8u) ? -v : v;
}
__device__ __forceinline__ f32x2 fp4_dec2(unsigned b, float s) {
#if __has_builtin(__builtin_amdgcn_cvt_scalef32_pk_f32_fp4)
    return __builtin_amdgcn_cvt_scalef32_pk_f32_fp4(b, s, 0);
#else
    f32x2 r;
    r.x = fp4_dec1(b & 15u) * s;
    r.y = fp4_dec1((b >> 4) & 15u) * s;
    return r;
#endif
}

// dinv is a pure function of the bucket cursor: deg = cursor[n] - n*CAP.
__device__ __forceinline__ float dinv_of(int cur, int n) {
    return rsqrtf((float)(cur - n * CAP) + 1.0f);
}

// ---- setup: blocks [0,24) prep W frags; [24,24+gN) gstart; [24+gN,..) cursor init

__global__ __launch_bounds__(256) void k_setup(const float* __restrict__ W1,
                                               const float* __restrict__ W2,
                                               const float* __restrict__ W3,
                                               uint4* __restrict__ wfrag,
                                               const int* __restrict__ batch,
                                               int* __restrict__ gstart,
                                               int* __restrict__ cursor, int N, int gN) {
    if (blockIdx.x < 24) {
        // W frag: (c,nt,i=nl*4+q): 8 f16 = W[k=c*32+q*8+j][n=nt*16+nl] at
        // swizzled index i^((nl>>1)&7); layer stride 2048 frags = 32 KB.
        int gid = blockIdx.x * 256 + threadIdx.x;       // 0..6143
        int layer = gid >> 11;
        int fr = gid & 2047;
        int c = fr >> 9;
        int nt = (fr >> 6) & 7;
        int i = fr & 63;
        int nl = i >> 2, q = i & 3;
        int iS = i ^ ((nl >> 1) & 7);
        int n = nt * 16 + nl;
        int k0 = c * 32 + q * 8;
        const float* W = (layer == 0) ? W1 : (layer == 1) ? W2 : W3;
        union { unsigned short s[8]; uint4 u; } pk;
        #pragma unroll
        for (int j = 0; j < 8; j++)
            pk.s[j] = h16(W[(k0 + j) * NCH + n]);
        wfrag[layer * 2048 + (c * 8 + nt) * 64 + iS] = pk.u;
    } else if (blockIdx.x < 24 + gN) {
        int i = (blockIdx.x - 24) * 256 + threadIdx.x;
        if (i >= N) return;
        int b = batch[i];
        int prev = (i == 0) ? -1 : batch[i - 1];
        for (int g = prev + 1; g <= b; g++) gstart[g] = i;
        if (i == N - 1) {
            for (int g = b + 1; g <= NGRAPH; g++) gstart[g] = N;
        }
    } else {
        int i = (blockIdx.x - 24 - gN) * 256 + threadIdx.x;
        if (i < N) cursor[i] = i * CAP;
    }
}

// XCD-localized scatter (round-7 win: plain stores suffer cross-XCD
// write-allocate amplification; 8 dst-ranges keyed by blockIdx&7 fix it).
// Proven scalar form.
__global__ __launch_bounds__(256) void k_fill(const int* __restrict__ src,
                                              const int* __restrict__ dst,
                                              int* __restrict__ cursor,
                                              int* __restrict__ edge_src, int E, int N) {
    int range = blockIdx.x & 7;
    int chunk = blockIdx.x >> 3;
    int r0 = (range * N) >> 3;
    int r1 = ((range + 1) * N) >> 3;
    int e = chunk * 256 + threadIdx.x;
    if (e >= E) return;
    int d = dst[e];
    if (d >= r0 && d < r1) {
        int p = atomicAdd(&cursor[d], 1);
        if (p < (d + 1) * CAP) edge_src[p] = src[e];   // guard never fires (max deg ~45)
    }
}

// ---- MFMA GEMM: fp4 table out = dinv[r] * (A[N,128] @ W) ----
// Table rows are fp4 e2m1 with per-row power-of-2 scale -> one row = 64 B,
// full table = 3.2 MB < 4 MiB per-XCD L2, single-pass gather keeps R6
// structure AND gets residency. Scale array Sc[row] (f32 pow2, 200 KB).
// Pad row rg==N written zero in table and Sc.
// A modes: a_fp32=1 -> raw fp32 (layer 1); a_fp32=0 -> f16 rows (hb).

__global__ __launch_bounds__(256) void k_mmgemm(const void* __restrict__ Araw,
                                                const uint4* __restrict__ wfrag,
                                                const int* __restrict__ cursor,
                                                unsigned* __restrict__ D,
                                                float* __restrict__ Sc, int N,
                                                int a_fp32) {
    __shared__ uint4 Wl[2048];           // 32 KB
    int t = threadIdx.x;
    #pragma unroll
    for (int i = 0; i < 8; i++) Wl[i * 256 + t] = wfrag[i * 256 + t];

    int wv = t >> 6, lane = t & 63;
    int rowW = blockIdx.x * 64 + wv * 16;
    int m = lane & 15, q = lane >> 4;
    int aRow = rowW + m;

    union { uint4 u; h8 h; } a[4];
    if (a_fp32) {
        const float* Af = (const float*)Araw;
        #pragma unroll
        for (int c = 0; c < 4; c++) {
            union { _Float16 h[8]; uint4 u; } pk;
            #pragma unroll
            for (int j = 0; j < 8; j++) pk.h[j] = (_Float16)0.f;
            if (aRow < N) {
                float4 v0 = *reinterpret_cast<const float4*>(&Af[(size_t)aRow * NCH + c * 32 + q * 8]);
                float4 v1 = *reinterpret_cast<const float4*>(&Af[(size_t)aRow * NCH + c * 32 + q * 8 + 4]);
                pk.h[0] = (_Float16)v0.x; pk.h[1] = (_Float16)v0.y;
                pk.h[2] = (_Float16)v0.z; pk.h[3] = (_Float16)v0.w;
                pk.h[4] = (_Float16)v1.x; pk.h[5] = (_Float16)v1.y;
                pk.h[6] = (_Float16)v1.z; pk.h[7] = (_Float16)v1.w;
            }
            a[c].u = pk.u;
        }
    } else {
        const unsigned* A = (const unsigned*)Araw;
        #pragma unroll
        for (int c = 0; c < 4; c++) {
            a[c].u = make_uint4(0, 0, 0, 0);
            if (aRow < N)
                a[c].u = *reinterpret_cast<const uint4*>(&A[(size_t)aRow * 64 + c * 16 + q * 4]);
        }
    }

    __syncthreads();

    int iS = (m * 4 + q) ^ ((m >> 1) & 7);

    f32x4 acc[8];
    #pragma unroll
    for (int nt = 0; nt < 8; nt++) acc[nt] = (f32x4){0.f, 0.f, 0.f, 0.f};

    #pragma unroll
    for (int c = 0; c < 4; c++) {
        #pragma unroll
        for (int nt = 0; nt < 8; nt++) {
            union { uint4 u; h8 h; } b;
            b.u = Wl[(c * 8 + nt) * 64 + iS];
            acc[nt] = __builtin_amdgcn_mfma_f32_16x16x32_f16(a[c].h, b.h, acc[nt], 0, 0, 0);
        }
    }

    float dn[4];
    #pragma unroll
    for (int r = 0; r < 4; r++) {
        int rg = rowW + q * 4 + r;
        dn[r] = (rg < N) ? dinv_of(cursor[rg], rg) : 0.0f;
    }

    // per-row abs-max (over nt locally, then 16-lane m-group shfl tree) ->
    // power-of-2 scale s_r = 2^ceil(log2(max/6)); lane m==0 stores Sc[rg].
    float sr[4];
    #pragma unroll
    for (int r = 0; r < 4; r++) {
        float mx = 0.f;
        #pragma unroll
        for (int nt = 0; nt < 8; nt++) mx = fmaxf(mx, fabsf(acc[nt][r] * dn[r]));
        mx = fmaxf(mx, __shfl_xor(mx, 1, 64));
        mx = fmaxf(mx, __shfl_xor(mx, 2, 64));
        mx = fmaxf(mx, __shfl_xor(mx, 4, 64));
        mx = fmaxf(mx, __shfl_xor(mx, 8, 64));
        float s = exp2f(ceilf(log2f(fmaxf(mx, 1e-30f) * (1.0f / 6.0f))));
        sr[r] = s;
        int rg = rowW + q * 4 + r;
        if (m == 0 && rg <= N) Sc[rg] = s;
    }

    // fp4 epilogue: even-m lane packs byte for channels (ch, ch+1) via
    // partner shfl; byte merges shfl_xor(2)<<8, shfl_xor(4)<<16 build the
    // dword (8 ch); lanes m%8==0 store. Row = 16 dwords = 64 B.
    #pragma unroll
    for (int nt = 0; nt < 8; nt++) {
        #pragma unroll
        for (int r = 0; r < 4; r++) {
            int rg = rowW + q * 4 + r;
            float v = acc[nt][r] * dn[r];
            float vp = __shfl_xor(v, 1, 64);
            unsigned b = fp4_enc_byte(v, vp, sr[r]);
            b |= ((unsigned)__shfl_xor((int)b, 2, 64)) << 8;
            b |= ((unsigned)__shfl_xor((int)b, 4, 64)) << 16;
            if ((m & 7) == 0 && rg <= N)               // rg==N: zero pad row
                D[(size_t)rg * 16 + nt * 2 + (m >> 3)] = b;
        }
    }
}

// ---- gather: relu(dinv*(self + sum_edges) + b), fp4 table in, f16 out ----
// R6 single-pass structure; table 3.2 MB -> L2-resident on every XCD.
// THIS ROUND: cooperative SCALE gather — lane (lane&15) loads Sc for ITS
// edge in one gathered VMEM instr (replaces 16 broadcast loads/batch,
// the defect that cost R11 its residency win), then __shfl broadcasts
// scale alongside index. Remainder clamps myi->N BEFORE the Sc gather
// (entries past j1 are uninitialized workspace).

__global__ __launch_bounds__(256) void k_gather(const unsigned char* __restrict__ tab,
                                                const float* __restrict__ Sc,
                                                const float* __restrict__ bias,
                                                const int* __restrict__ cursor,
                                                const int* __restrict__ edge_src,
                                                unsigned* __restrict__ out, int N) {
    int wv = threadIdx.x >> 6;
    int lane = threadIdx.x & 63;
    int n = blockIdx.x * 4 + wv;
    if (n >= N) return;

    unsigned us = tab[(size_t)n * 64 + lane];
    f32x2 v0 = fp4_dec2(us, Sc[n]);
    float ax = v0.x, ay = v0.y;

    int j0 = n * CAP;
    int cur = cursor[n];
    int j1 = cur;
    if (j1 > j0 + CAP) j1 = j0 + CAP;

    int j = j0;
    for (; j + 16 <= j1; j += 16) {
        int myi = edge_src[j + (lane & 15)];   // one coalesced 64-B request
        float mysc = Sc[myi];                  // ONE gathered request: 16 scales
        unsigned u[16];
        float sc[16];
        #pragma unroll
        for (int i = 0; i < 16; i++) {
            int bi = __shfl(myi, i, 16);       // in-register broadcasts
            sc[i] = __shfl(mysc, i, 16);
            u[i] = tab[(size_t)bi * 64 + lane];
        }
        #pragma unroll
        for (int i = 0; i < 16; i++) {
            f32x2 v = fp4_dec2(u[i], sc[i]);
            ax += v.x; ay += v.y;
        }
    }
    int r = j1 - j;
    if (r > 0) {
        int ji = j + (lane & 15);
        int myi = (ji < j1) ? edge_src[ji] : N;   // clamp BEFORE Sc gather
        float mysc = Sc[myi];
        unsigned u[16];
        float sc[16];
        #pragma unroll
        for (int i = 0; i < 16; i++) {
            int bi = __shfl(myi, i, 16);
            sc[i] = __shfl(mysc, i, 16);
            u[i] = tab[(size_t)bi * 64 + lane];
        }
        #pragma unroll
        for (int i = 0; i < 16; i++) {
            f32x2 v = fp4_dec2(u[i], sc[i]);
            ax += v.x; ay += v.y;
        }
    }

    float dn = dinv_of(cur, n);
    float2 bb = reinterpret_cast<const float2*>(bias)[lane];
    float ox = fmaxf(ax * dn + bb.x, 0.0f);
    float oy = fmaxf(ay * dn + bb.y, 0.0f);
    out[(size_t)n * 64 + lane] = pkh(ox, oy);
}

// ---------------- pooling (f16 in, fp32 partials) ----------------

__global__ __launch_bounds__(256) void k_poolA(const unsigned* __restrict__ h,
                                               const int* __restrict__ gstart,
                                               float* __restrict__ partial) {
    int g = blockIdx.x >> 4;
    int s = blockIdx.x & (SUB - 1);
    int c2 = threadIdx.x & 63;
    int r = threadIdx.x >> 6;          // 0..3
    int j0 = gstart[g], j1 = gstart[g + 1];
    int len = j1 - j0;
    int chunk = (len + SUB - 1) / SUB;
    int a0 = j0 + s * chunk;
    int a1 = a0 + chunk; if (a1 > j1) a1 = j1;
    float ax = 0.0f, ay = 0.0f;
    for (int j = a0 + r; j < a1; j += 4) {
        unsigned u = h[(size_t)j * 64 + c2];
        ax += flo(u); ay += fhi(u);
    }
    __shared__ float2 sh[4][64];
    sh[r][c2] = make_float2(ax, ay);
    __syncthreads();
    if (r == 0) {
        float sx = sh[0][c2].x + sh[1][c2].x + sh[2][c2].x + sh[3][c2].x;
        float sy = sh[0][c2].y + sh[1][c2].y + sh[2][c2].y + sh[3][c2].y;
        reinterpret_cast<float2*>(partial)[(size_t)(g * SUB + s) * 64 + c2] =
            make_float2(sx, sy);
    }
}

__global__ __launch_bounds__(128) void k_finalize(const float* __restrict__ partial,
                                                  const int* __restrict__ gstart,
                                                  const float* __restrict__ Wc,
                                                  const float* __restrict__ bc,
                                                  float* __restrict__ out) {
    int g = blockIdx.x;
    int c = threadIdx.x;
    float s = 0.0f;
    #pragma unroll
    for (int i = 0; i < SUB; i++) s += partial[(size_t)(g * SUB + i) * NCH + c];
    int len = gstart[g + 1] - gstart[g];
    __shared__ float sh[128];
    sh[c] = s / fmaxf((float)len, 1.0f);
    __syncthreads();
    if (c < 2) {
        float o = 0.0f;
        for (int k = 0; k < NCH; k++) o += sh[k] * Wc[k * 2 + c];
        out[g * 2 + c] = o + bc[c];
    }
}

// ---------------- launcher ----------------

extern "C" void kernel_launch(void* const* d_in, const int* in_sizes, int n_in,
                              void* d_out, int out_size, void* d_ws, size_t ws_size,
                              hipStream_t stream) {
    const float* x   = (const float*)d_in[0];
    const int* eidx  = (const int*)d_in[1];
    const int* batch = (const int*)d_in[2];
    const float* W1 = (const float*)d_in[3];
    const float* b1 = (const float*)d_in[4];
    const float* W2 = (const float*)d_in[5];
    const float* b2 = (const float*)d_in[6];
    const float* W3 = (const float*)d_in[7];
    const float* b3 = (const float*)d_in[8];
    const float* Wc = (const float*)d_in[9];
    const float* bc = (const float*)d_in[10];
    float* out = (float*)d_out;

    int N = in_sizes[0] / NCH;
    int E = in_sizes[1] / 2;
    const int* src = eidx;
    const int* dst = eidx + E;

    char* w = (char*)d_ws;
    auto alloc = [&](size_t bytes) -> void* {
        void* p = (void*)w;
        w += (bytes + 511) & ~(size_t)511;
        return p;
    };
    int*      cursor   = (int*)alloc((size_t)N * 4);
    int*      edge_src = (int*)alloc((size_t)N * CAP * 4);   // 12.8 MB buckets
    uint4*    wfrag    = (uint4*)alloc((size_t)3 * 2048 * 16);
    unsigned* hwD      = (unsigned*)alloc((size_t)(N + 64) * 64);  // fp4 table, 64-B rows
    float*    hwSc     = (float*)alloc((size_t)(N + 64) * 4);      // per-row pow2 scales
    unsigned* hbA      = (unsigned*)alloc((size_t)N * 64 * 4);     // f16 activations
    unsigned* hbB      = (unsigned*)alloc((size_t)N * 64 * 4);
    float*    partial  = (float*)alloc((size_t)NGRAPH * SUB * NCH * 4);
    int*      gstart   = (int*)alloc((size_t)(NGRAPH + 1) * 4);

    int gE = (E + 255) / 256;
    int gN = (N + 255) / 256;

    k_setup<<<24 + 2 * gN, 256, 0, stream>>>(W1, W2, W3, wfrag, batch, gstart, cursor, N, gN);
    k_fill<<<gE * 8, 256, 0, stream>>>(src, dst, cursor, edge_src, E, N);

    int gM = (N + 63) / 64;
    int gA = (N + 3) / 4;
    const unsigned char* tab = (const unsigned char*)hwD;
    // layer 1 (reads fp32 x directly)
    k_mmgemm<<<gM, 256, 0, stream>>>(x, wfrag, cursor, hwD, hwSc, N, 1);
    k_gather<<<gA, 256, 0, stream>>>(tab, hwSc, b1, cursor, edge_src, hbA, N);
    // layer 2
    k_mmgemm<<<gM, 256, 0, stream>>>(hbA, wfrag + 2048, cursor, hwD, hwSc, N, 0);
    k_gather<<<gA, 256, 0, stream>>>(tab, hwSc, b2, cursor, edge_src, hbB, N);
    // layer 3
    k_mmgemm<<<gM, 256, 0, stream>>>(hbB, wfrag + 4096, cursor, hwD, hwSc, N, 0);
    k_gather<<<gA, 256, 0, stream>>>(tab, hwSc, b3, cursor, edge_src, hbA, N);

    k_poolA<<<NGRAPH * SUB, 256, 0, stream>>>(hbA, gstart, partial);
    k_finalize<<<NGRAPH, 128, 0, stream>>>(partial, gstart, Wc, bc, out);
}

// Round 13
// 226.604 us; speedup vs baseline: 1.1612x; 1.1612x over previous
//
#include <hip/hip_runtime.h>

#define NCH 128
#define NGRAPH 64
#define SUB 16
#define CAP 64          // per-node edge bucket capacity (max in-degree ~45 for Poisson(16))

typedef _Float16 h8 __attribute__((ext_vector_type(8)));
typedef float f32x4 __attribute__((ext_vector_type(4)));
typedef float f32x2 __attribute__((ext_vector_type(2)));

// ---------------- f16/fp8 helpers ----------------

__device__ __forceinline__ unsigned pkh(float a, float b) {
    union { _Float16 h[2]; unsigned u; } x;
    x.h[0] = (_Float16)a; x.h[1] = (_Float16)b;
    return x.u;
}
__device__ __forceinline__ float flo(unsigned u) {
    union { unsigned u; _Float16 h[2]; } x; x.u = u; return (float)x.h[0];
}
__device__ __forceinline__ float fhi(unsigned u) {
    union { unsigned u; _Float16 h[2]; } x; x.u = u; return (float)x.h[1];
}
__device__ __forceinline__ unsigned short h16(float a) {
    union { _Float16 h; unsigned short s; } x; x.h = (_Float16)a; return x.s;
}

// dinv is a pure function of the bucket cursor: deg = cursor[n] - n*CAP.
__device__ __forceinline__ float dinv_of(int cur, int n) {
    return rsqrtf((float)(cur - n * CAP) + 1.0f);
}

// ---- setup: blocks [0,24) prep W frags; [24,24+gN) gstart; [24+gN,..) cursor init

__global__ __launch_bounds__(256) void k_setup(const float* __restrict__ W1,
                                               const float* __restrict__ W2,
                                               const float* __restrict__ W3,
                                               uint4* __restrict__ wfrag,
                                               const int* __restrict__ batch,
                                               int* __restrict__ gstart,
                                               int* __restrict__ cursor, int N, int gN) {
    if (blockIdx.x < 24) {
        // W frag: (c,nt,i=nl*4+q): 8 f16 = W[k=c*32+q*8+j][n=nt*16+nl] at
        // swizzled index i^((nl>>1)&7); layer stride 2048 frags = 32 KB.
        int gid = blockIdx.x * 256 + threadIdx.x;       // 0..6143
        int layer = gid >> 11;
        int fr = gid & 2047;
        int c = fr >> 9;
        int nt = (fr >> 6) & 7;
        int i = fr & 63;
        int nl = i >> 2, q = i & 3;
        int iS = i ^ ((nl >> 1) & 7);
        int n = nt * 16 + nl;
        int k0 = c * 32 + q * 8;
        const float* W = (layer == 0) ? W1 : (layer == 1) ? W2 : W3;
        union { unsigned short s[8]; uint4 u; } pk;
        #pragma unroll
        for (int j = 0; j < 8; j++)
            pk.s[j] = h16(W[(k0 + j) * NCH + n]);
        wfrag[layer * 2048 + (c * 8 + nt) * 64 + iS] = pk.u;
    } else if (blockIdx.x < 24 + gN) {
        int i = (blockIdx.x - 24) * 256 + threadIdx.x;
        if (i >= N) return;
        int b = batch[i];
        int prev = (i == 0) ? -1 : batch[i - 1];
        for (int g = prev + 1; g <= b; g++) gstart[g] = i;
        if (i == N - 1) {
            for (int g = b + 1; g <= NGRAPH; g++) gstart[g] = N;
        }
    } else {
        int i = (blockIdx.x - 24 - gN) * 256 + threadIdx.x;
        if (i < N) cursor[i] = i * CAP;
    }
}

// XCD-localized scatter (round-7 win: plain stores suffer cross-XCD
// write-allocate amplification; 8 dst-ranges keyed by blockIdx&7 fix it).
// Proven scalar form.
__global__ __launch_bounds__(256) void k_fill(const int* __restrict__ src,
                                              const int* __restrict__ dst,
                                              int* __restrict__ cursor,
                                              int* __restrict__ edge_src, int E, int N) {
    int range = blockIdx.x & 7;
    int chunk = blockIdx.x >> 3;
    int r0 = (range * N) >> 3;
    int r1 = ((range + 1) * N) >> 3;
    int e = chunk * 256 + threadIdx.x;
    if (e >= E) return;
    int d = dst[e];
    if (d >= r0 && d < r1) {
        int p = atomicAdd(&cursor[d], 1);
        if (p < (d + 1) * CAP) edge_src[p] = src[e];   // guard never fires (max deg ~45)
    }
}

// ---- MFMA GEMM: D[N,128](fp8 e4m3) = dinv[r] * (A[N,128] @ W) ----
// R6 proven form (247.3us best): table rows fp8, 128 B = one cache line,
// zero pad row at rg==N. Byte p of row = channel p (verified linear).
// A modes: a_fp32=1 -> raw fp32 (layer 1); a_fp32=0 -> f16 rows (hb).

__global__ __launch_bounds__(256) void k_mmgemm(const void* __restrict__ Araw,
                                                const uint4* __restrict__ wfrag,
                                                const int* __restrict__ cursor,
                                                unsigned* __restrict__ D, int N,
                                                int a_fp32) {
    __shared__ uint4 Wl[2048];           // 32 KB
    int t = threadIdx.x;
    #pragma unroll
    for (int i = 0; i < 8; i++) Wl[i * 256 + t] = wfrag[i * 256 + t];

    int wv = t >> 6, lane = t & 63;
    int rowW = blockIdx.x * 64 + wv * 16;
    int m = lane & 15, q = lane >> 4;
    int aRow = rowW + m;

    union { uint4 u; h8 h; } a[4];
    if (a_fp32) {
        const float* Af = (const float*)Araw;
        #pragma unroll
        for (int c = 0; c < 4; c++) {
            union { _Float16 h[8]; uint4 u; } pk;
            #pragma unroll
            for (int j = 0; j < 8; j++) pk.h[j] = (_Float16)0.f;
            if (aRow < N) {
                float4 v0 = *reinterpret_cast<const float4*>(&Af[(size_t)aRow * NCH + c * 32 + q * 8]);
                float4 v1 = *reinterpret_cast<const float4*>(&Af[(size_t)aRow * NCH + c * 32 + q * 8 + 4]);
                pk.h[0] = (_Float16)v0.x; pk.h[1] = (_Float16)v0.y;
                pk.h[2] = (_Float16)v0.z; pk.h[3] = (_Float16)v0.w;
                pk.h[4] = (_Float16)v1.x; pk.h[5] = (_Float16)v1.y;
                pk.h[6] = (_Float16)v1.z; pk.h[7] = (_Float16)v1.w;
            }
            a[c].u = pk.u;
        }
    } else {
        const unsigned* A = (const unsigned*)Araw;
        #pragma unroll
        for (int c = 0; c < 4; c++) {
            a[c].u = make_uint4(0, 0, 0, 0);
            if (aRow < N)
                a[c].u = *reinterpret_cast<const uint4*>(&A[(size_t)aRow * 64 + c * 16 + q * 4]);
        }
    }

    __syncthreads();

    int iS = (m * 4 + q) ^ ((m >> 1) & 7);

    f32x4 acc[8];
    #pragma unroll
    for (int nt = 0; nt < 8; nt++) acc[nt] = (f32x4){0.f, 0.f, 0.f, 0.f};

    #pragma unroll
    for (int c = 0; c < 4; c++) {
        #pragma unroll
        for (int nt = 0; nt < 8; nt++) {
            union { uint4 u; h8 h; } b;
            b.u = Wl[(c * 8 + nt) * 64 + iS];
            acc[nt] = __builtin_amdgcn_mfma_f32_16x16x32_f16(a[c].h, b.h, acc[nt], 0, 0, 0);
        }
    }

    float dn[4];
    #pragma unroll
    for (int r = 0; r < 4; r++) {
        int rg = rowW + q * 4 + r;
        dn[r] = (rg < N) ? dinv_of(cursor[rg], rg) : 0.0f;
    }
    // fp8 epilogue: each lane packs its own byte (channel nt*16+m), merge
    // bytes across lanes m..m+3 via two shfl_xor, lanes m%4==0 store a dword.
    #pragma unroll
    for (int nt = 0; nt < 8; nt++) {
        #pragma unroll
        for (int r = 0; r < 4; r++) {
            int rg = rowW + q * 4 + r;
            float v = acc[nt][r] * dn[r];
            unsigned b = __builtin_amdgcn_cvt_pk_fp8_f32(v, v, 0, false) & 0xffu;
            b |= ((unsigned)__shfl_xor((int)b, 1, 64)) << 8;
            b |= ((unsigned)__shfl_xor((int)b, 2, 64)) << 16;
            if ((lane & 3) == 0 && rg <= N)            // rg==N: zero pad row
                D[(size_t)rg * 32 + nt * 4 + (m >> 2)] = b;
        }
    }
}

// ---- gather: relu(dinv*(self + sum_edges) + b), fp8 table, DUAL-NODE wave ----
// THIS ROUND: lanes 0-31 serve node A, lanes 32-63 node B. Each lane reads
// one dword (4 fp8 ch) of a 128-B row -> ONE VMEM instruction fetches rows
// for TWO edges (one per node). Row-instrs/node ~23 -> ~13 (shared batches
// amortize pad reads); index loads dedupe 2:1 (R5 coop scheme, shfl src
// (half<<5)+i); two independent dep chains per wave hide latency better.
// Per-channel summation order identical to R6 -> bitwise-same output.

__global__ __launch_bounds__(256) void k_gather(const unsigned* __restrict__ hw,
                                                const float* __restrict__ bias,
                                                const int* __restrict__ cursor,
                                                const int* __restrict__ edge_src,
                                                uint2* __restrict__ out, int N) {
    int wv = threadIdx.x >> 6;
    int lane = threadIdx.x & 63;
    int half = lane >> 5;              // 0: node A, 1: node B
    int c4 = lane & 31;                // dword index within 128-B row
    int n = blockIdx.x * 8 + wv * 2 + half;
    bool act = (n < N);
    int nn = act ? n : N;              // pad row N: zeros

    // self term: 4 channels per lane
    unsigned vs = hw[(size_t)nn * 32 + c4];
    f32x2 slo = __builtin_amdgcn_cvt_pk_f32_fp8((int)vs, false);
    f32x2 shi = __builtin_amdgcn_cvt_pk_f32_fp8((int)vs, true);
    float a0 = slo.x, a1 = slo.y, a2 = shi.x, a3 = shi.y;

    int cur = act ? cursor[n] : 0;
    int j0 = act ? n * CAP : 0;
    int j1 = act ? cur : 0;
    if (j1 > j0 + CAP) j1 = j0 + CAP;
    int deg = j1 - j0;
    int odeg = __shfl_xor(deg, 32, 64);
    int nb = (((deg > odeg) ? deg : odeg) + 15) >> 4;

    for (int b = 0; b < nb; b++) {
        int ji = j0 + b * 16 + (lane & 15);
        int myi = (ji < j1) ? edge_src[ji] : N;    // predicated coalesced load
        unsigned u[16];
        #pragma unroll
        for (int i = 0; i < 16; i++) {
            int bi = __shfl(myi, (half << 5) + i, 64);   // A<-lanes 0.., B<-lanes 32..
            u[i] = hw[(size_t)bi * 32 + c4];
        }
        #pragma unroll
        for (int i = 0; i < 16; i++) {
            f32x2 vlo = __builtin_amdgcn_cvt_pk_f32_fp8((int)u[i], false);
            f32x2 vhi = __builtin_amdgcn_cvt_pk_f32_fp8((int)u[i], true);
            a0 += vlo.x; a1 += vlo.y; a2 += vhi.x; a3 += vhi.y;
        }
    }

    if (act) {
        float dn = dinv_of(cur, n);
        float4 bb = reinterpret_cast<const float4*>(bias)[c4];   // ch 4c4..4c4+3
        uint2 o;
        o.x = pkh(fmaxf(a0 * dn + bb.x, 0.0f), fmaxf(a1 * dn + bb.y, 0.0f));
        o.y = pkh(fmaxf(a2 * dn + bb.z, 0.0f), fmaxf(a3 * dn + bb.w, 0.0f));
        out[(size_t)n * 32 + c4] = o;              // 8 B/lane, coalesced
    }
}

// ---------------- pooling (f16 in, fp32 partials) ----------------

__global__ __launch_bounds__(256) void k_poolA(const unsigned* __restrict__ h,
                                               const int* __restrict__ gstart,
                                               float* __restrict__ partial) {
    int g = blockIdx.x >> 4;
    int s = blockIdx.x & (SUB - 1);
    int c2 = threadIdx.x & 63;
    int r = threadIdx.x >> 6;          // 0..3
    int j0 = gstart[g], j1 = gstart[g + 1];
    int len = j1 - j0;
    int chunk = (len + SUB - 1) / SUB;
    int a0 = j0 + s * chunk;
    int a1 = a0 + chunk; if (a1 > j1) a1 = j1;
    float ax = 0.0f, ay = 0.0f;
    for (int j = a0 + r; j < a1; j += 4) {
        unsigned u = h[(size_t)j * 64 + c2];
        ax += flo(u); ay += fhi(u);
    }
    __shared__ float2 sh[4][64];
    sh[r][c2] = make_float2(ax, ay);
    __syncthreads();
    if (r == 0) {
        float sx = sh[0][c2].x + sh[1][c2].x + sh[2][c2].x + sh[3][c2].x;
        float sy = sh[0][c2].y + sh[1][c2].y + sh[2][c2].y + sh[3][c2].y;
        reinterpret_cast<float2*>(partial)[(size_t)(g * SUB + s) * 64 + c2] =
            make_float2(sx, sy);
    }
}

__global__ __launch_bounds__(128) void k_finalize(const float* __restrict__ partial,
                                                  const int* __restrict__ gstart,
                                                  const float* __restrict__ Wc,
                                                  const float* __restrict__ bc,
                                                  float* __restrict__ out) {
    int g = blockIdx.x;
    int c = threadIdx.x;
    float s = 0.0f;
    #pragma unroll
    for (int i = 0; i < SUB; i++) s += partial[(size_t)(g * SUB + i) * NCH + c];
    int len = gstart[g + 1] - gstart[g];
    __shared__ float sh[128];
    sh[c] = s / fmaxf((float)len, 1.0f);
    __syncthreads();
    if (c < 2) {
        float o = 0.0f;
        for (int k = 0; k < NCH; k++) o += sh[k] * Wc[k * 2 + c];
        out[g * 2 + c] = o + bc[c];
    }
}

// ---------------- launcher ----------------

extern "C" void kernel_launch(void* const* d_in, const int* in_sizes, int n_in,
                              void* d_out, int out_size, void* d_ws, size_t ws_size,
                              hipStream_t stream) {
    const float* x   = (const float*)d_in[0];
    const int* eidx  = (const int*)d_in[1];
    const int* batch = (const int*)d_in[2];
    const float* W1 = (const float*)d_in[3];
    const float* b1 = (const float*)d_in[4];
    const float* W2 = (const float*)d_in[5];
    const float* b2 = (const float*)d_in[6];
    const float* W3 = (const float*)d_in[7];
    const float* b3 = (const float*)d_in[8];
    const float* Wc = (const float*)d_in[9];
    const float* bc = (const float*)d_in[10];
    float* out = (float*)d_out;

    int N = in_sizes[0] / NCH;
    int E = in_sizes[1] / 2;
    const int* src = eidx;
    const int* dst = eidx + E;

    char* w = (char*)d_ws;
    auto alloc = [&](size_t bytes) -> void* {
        void* p = (void*)w;
        w += (bytes + 511) & ~(size_t)511;
        return p;
    };
    int*      cursor    = (int*)alloc((size_t)N * 4);
    int*      edge_src  = (int*)alloc((size_t)N * CAP * 4);   // 12.8 MB buckets
    uint4*    wfrag     = (uint4*)alloc((size_t)3 * 2048 * 16);
    unsigned* hwD       = (unsigned*)alloc((size_t)(N + 64) * 128);  // fp8 table + pad row
    unsigned* hbA       = (unsigned*)alloc((size_t)N * 64 * 4);
    unsigned* hbB       = (unsigned*)alloc((size_t)N * 64 * 4);
    float*    partial   = (float*)alloc((size_t)NGRAPH * SUB * NCH * 4);
    int*      gstart    = (int*)alloc((size_t)(NGRAPH + 1) * 4);

    int gE = (E + 255) / 256;
    int gN = (N + 255) / 256;

    k_setup<<<24 + 2 * gN, 256, 0, stream>>>(W1, W2, W3, wfrag, batch, gstart, cursor, N, gN);
    k_fill<<<gE * 8, 256, 0, stream>>>(src, dst, cursor, edge_src, E, N);

    int gM = (N + 63) / 64;
    int gA = (N + 7) / 8;          // dual-node waves: 8 nodes per block
    // layer 1 (reads fp32 x directly)
    k_mmgemm<<<gM, 256, 0, stream>>>(x, wfrag, cursor, hwD, N, 1);
    k_gather<<<gA, 256, 0, stream>>>(hwD, b1, cursor, edge_src, (uint2*)hbA, N);
    // layer 2
    k_mmgemm<<<gM, 256, 0, stream>>>(hbA, wfrag + 2048, cursor, hwD, N, 0);
    k_gather<<<gA, 256, 0, stream>>>(hwD, b2, cursor, edge_src, (uint2*)hbB, N);
    // layer 3
    k_mmgemm<<<gM, 256, 0, stream>>>(hbB, wfrag + 4096, cursor, hwD, N, 0);
    k_gather<<<gA, 256, 0, stream>>>(hwD, b3, cursor, edge_src, (uint2*)hbA, N);

    k_poolA<<<NGRAPH * SUB, 256, 0, stream>>>(hbA, gstart, partial);
    k_finalize<<<NGRAPH, 128, 0, stream>>>(partial, gstart, Wc, bc, out);
}